// Round 7
// baseline (52.947 us; speedup 1.0000x reference)
//
#include <hip/hip_runtime.h>
#include <math.h>

#define NK 32           // knots
#define NP 36           // NK + 4 (system size)
#define NA 37           // augmented columns (incl. rhs)
#define LDA 40          // padded LDS row stride (floats)
#define PX 8            // pixels per thread in apply

// hardware v_sqrt_f32 (~1 ulp) — __sqrtf collides with glibc math.h macros
__device__ __forceinline__ float hw_sqrtf(float x) {
    return __builtin_amdgcn_sqrtf(x);
}

// ---------------------------------------------------------------------------
// Full-wave (64-lane) max of an unsigned via DPP; result is wave-uniform
// (returned through readlane 63 -> SGPR). All-VALU, no LDS latency.
// ---------------------------------------------------------------------------
__device__ __forceinline__ unsigned wave_max64(unsigned x) {
    unsigned t;
    t = (unsigned)__builtin_amdgcn_update_dpp(0, (int)x, 0x111, 0xF, 0xF, true); x = x > t ? x : t; // row_shr:1
    t = (unsigned)__builtin_amdgcn_update_dpp(0, (int)x, 0x112, 0xF, 0xF, true); x = x > t ? x : t; // row_shr:2
    t = (unsigned)__builtin_amdgcn_update_dpp(0, (int)x, 0x114, 0xF, 0xF, true); x = x > t ? x : t; // row_shr:4
    t = (unsigned)__builtin_amdgcn_update_dpp(0, (int)x, 0x118, 0xF, 0xF, true); x = x > t ? x : t; // row_shr:8
    t = (unsigned)__builtin_amdgcn_update_dpp(0, (int)x, 0x142, 0xA, 0xF, true); x = x > t ? x : t; // row_bcast:15
    t = (unsigned)__builtin_amdgcn_update_dpp(0, (int)x, 0x143, 0xC, 0xF, true); x = x > t ? x : t; // row_bcast:31
    return (unsigned)__builtin_amdgcn_readlane((int)x, 63);
}

// broadcast float from lane sl (wave-uniform SGPR) — pure bit ops
__device__ __forceinline__ float bcastf(float v, int sl) {
    return __int_as_float(__builtin_amdgcn_readlane(__float_as_int(v), sl));
}

// ---------------------------------------------------------------------------
// Stage 1: LDS-distributed Gauss-Jordan with partial pivoting.
// One block (256 threads) per (batch,channel) system; matrix A[36][40] lives
// in LDS (no reliance on register promotion). Each thread owns 6 static
// (r,c) elements. Per step: every wave redundantly computes the pivot via
// DPP argmax over column k (identical result in all waves -> no publish
// barrier), then all threads update their elements; ONE barrier per step.
// Pivot rows are never normalized in place; x[k] = A[p_k][36]/A[p_k][k].
// ---------------------------------------------------------------------------
__global__ __launch_bounds__(256, 1) void tps_solve(const float* __restrict__ params,
                                                    float* __restrict__ Wout) {
    int sys = blockIdx.x;
    int b   = sys / 3;
    int ch  = sys % 3;
    const float* pp = params + (size_t)b * (6 * NK + 3);

    __shared__ float A[NP * LDA];
    __shared__ float sxs[NK * 3];
    __shared__ int   s_pk[NP];

    int tid = threadIdx.x;
    if (tid < NK * 3) sxs[tid] = pp[tid];
    __syncthreads();

    float lam = pp[6 * NK + ch];

    // Static element assignment: e = tid + j*256, (r,c) = (e/37, e%37).
    int rj[6], cj[6], aoff[6], roff[6];
    #pragma unroll
    for (int j = 0; j < 6; ++j) {
        int e = tid + j * 256;
        int rr = e / NA, cc = e - rr * NA;
        rj[j] = rr; cj[j] = cc;
        roff[j] = rr * LDA;
        aoff[j] = rr * LDA + cc;
        if (e < NP * NA) {
            float v;
            if (rr < NK) {
                if (cc < NK) {
                    if (cc == rr) v = lam;                 // diag: dist=0, +lambda
                    else {
                        float dx = sxs[rr*3+0] - sxs[cc*3+0];
                        float dy = sxs[rr*3+1] - sxs[cc*3+1];
                        float dz = sxs[rr*3+2] - sxs[cc*3+2];
                        v = hw_sqrtf(dx*dx + dy*dy + dz*dz);
                    }
                } else if (cc == NK) v = 1.0f;
                else if (cc < NP)    v = sxs[rr*3 + (cc - 33)];
                else                 v = pp[3*NK + rr*3 + ch];   // rhs = ys[rr][ch]
            } else {
                if (cc < NK) v = (rr == NK) ? 1.0f : sxs[cc*3 + (rr - 33)];
                else         v = 0.0f;                    // zero 4x4+rhs block
            }
            A[aoff[j]] = v;
        }
    }
    __syncthreads();

    int lane = tid & 63;
    unsigned rowused = (lane < NP) ? 0u : 1u;   // per-lane flag, every wave

    for (int k = 0; k < NP; ++k) {
        // --- pivot: redundant per wave; lanes<36 read column k ---
        float cv = (lane < NP) ? A[lane * LDA + k] : 0.0f;
        unsigned packed = (__float_as_uint(fabsf(cv)) & 0xFFFFFFC0u) | (unsigned)lane;
        if (rowused) packed = 0u;
        int p = (int)(wave_max64(packed) & 63u);
        if (lane == p) rowused = 1u;
        float pv  = bcastf(cv, p);
        float inv = 1.0f / pv;
        if (tid == 0) s_pk[k] = p;

        // --- update: all threads, own elements. Writes: cc>k && rr!=p.
        // Reads: column k (never written here) and row p (never written). ---
        int pbase = p * LDA;
        #pragma unroll
        for (int j = 0; j < 6; ++j) {
            if (tid + j * 256 < NP * NA) {
                if (cj[j] > k && rj[j] != p) {
                    A[aoff[j]] -= A[roff[j] + k] * (inv * A[pbase + cj[j]]);
                }
            }
        }
        __syncthreads();
    }

    // extract: row p_k holds [0..0, piv_k, 0..0 | rhs'] -> x[k]
    if (tid < NP) {
        int p = s_pk[tid];
        float x = A[p * LDA + (NA - 1)] / A[p * LDA + tid];
        Wout[((size_t)b * NP + tid) * 4 + ch] = x;
    }
}

// ---------------------------------------------------------------------------
// Stage 2: per-pixel spline evaluation, PX=8 pixels (24 floats = 6 float4)
// per thread. fimg = raw.reshape(B,HW,3) is a linear reinterpretation, and
// the output reshape is the identity on flat layout. (unchanged — ~87% of
// achievable HBM BW already)
// ---------------------------------------------------------------------------
__global__ __launch_bounds__(256) void spline_apply(const float* __restrict__ raw,
                                                    const float* __restrict__ params,
                                                    const float4* __restrict__ Wk,
                                                    float* __restrict__ out,
                                                    int HW) {
    __shared__ float4 sX[NK];
    __shared__ float4 sW[NP];

    int b   = blockIdx.y;
    int tid = threadIdx.x;

    const float* pp = params + (size_t)b * (6 * NK + 3);
    if (tid < NK) sX[tid] = make_float4(pp[tid*3], pp[tid*3+1], pp[tid*3+2], 0.f);
    if (tid < NP) sW[tid] = Wk[(size_t)b * NP + tid];
    __syncthreads();

    int p8 = blockIdx.x * 256 + tid;          // 8-pixel group within batch
    if (p8 * PX >= HW) return;

    size_t off = (size_t)b * HW * 3 + (size_t)p8 * (PX * 3);
    const float4* src = (const float4*)(raw + off);
    float f[PX * 3];
    #pragma unroll
    for (int j = 0; j < PX * 3 / 4; ++j) {
        float4 v = src[j];
        f[j*4+0] = v.x; f[j*4+1] = v.y; f[j*4+2] = v.z; f[j*4+3] = v.w;
    }

    float4 wb  = sW[NK];                                    // bias row
    float4 w33 = sW[NK+1], w34 = sW[NK+2], w35 = sW[NK+3];  // linear rows
    float acc[PX * 3];
    #pragma unroll
    for (int p = 0; p < PX; ++p) {
        float c0 = f[p*3+0], c1 = f[p*3+1], c2 = f[p*3+2];
        acc[p*3+0] = wb.x + c0*w33.x + c1*w34.x + c2*w35.x;
        acc[p*3+1] = wb.y + c0*w33.y + c1*w34.y + c2*w35.y;
        acc[p*3+2] = wb.z + c0*w33.z + c1*w34.z + c2*w35.z;
    }

    #pragma unroll 4
    for (int k = 0; k < NK; ++k) {
        float4 x = sX[k];
        float4 w = sW[k];
        #pragma unroll
        for (int p = 0; p < PX; ++p) {
            float dx = f[p*3+0] - x.x;
            float dy = f[p*3+1] - x.y;
            float dz = f[p*3+2] - x.z;
            float d  = hw_sqrtf(dx*dx + dy*dy + dz*dz);
            acc[p*3+0] += d * w.x;
            acc[p*3+1] += d * w.y;
            acc[p*3+2] += d * w.z;
        }
    }

    float4* dst = (float4*)(out + off);
    #pragma unroll
    for (int j = 0; j < PX * 3 / 4; ++j)
        dst[j] = make_float4(acc[j*4+0], acc[j*4+1], acc[j*4+2], acc[j*4+3]);
}

extern "C" void kernel_launch(void* const* d_in, const int* in_sizes, int n_in,
                              void* d_out, int out_size, void* d_ws, size_t ws_size,
                              hipStream_t stream) {
    const float* raw    = (const float*)d_in[0];
    const float* params = (const float*)d_in[1];
    float* out = (float*)d_out;
    float* Wk  = (float*)d_ws;                 // [B][36][4] floats

    int B  = in_sizes[1] / (6 * NK + 3);
    int HW = in_sizes[0] / (B * 3);

    tps_solve<<<dim3(B * 3), dim3(256), 0, stream>>>(params, Wk);

    int groups = HW / PX;                      // HW = 200704, divisible by 8
    int bpb = (groups + 255) / 256;
    spline_apply<<<dim3(bpb, B), dim3(256), 0, stream>>>(
        raw, params, (const float4*)Wk, out, HW);
}

// Round 10
// 42.857 us; speedup vs baseline: 1.2354x; 1.2354x over previous
//
#include <hip/hip_runtime.h>
#include <math.h>

#define NK 32           // knots
#define NP 36           // NK + 4 (system size)
#define PX 8            // pixels per thread in apply

// hardware v_sqrt_f32 (~1 ulp) — __sqrtf collides with glibc math.h macros
__device__ __forceinline__ float hw_sqrtf(float x) {
    return __builtin_amdgcn_sqrtf(x);
}

// ---------------------------------------------------------------------------
// Full-wave (64-lane) max of an unsigned via DPP; result is wave-uniform
// (returned through readlane 63 -> SGPR). All-VALU, no LDS latency.
// Proven functional in R5/R6 (pivoted solves passed at absmax 0.125).
// ---------------------------------------------------------------------------
__device__ __forceinline__ unsigned wave_max64(unsigned x) {
    unsigned t;
    t = (unsigned)__builtin_amdgcn_update_dpp(0, (int)x, 0x111, 0xF, 0xF, true); x = x > t ? x : t; // row_shr:1
    t = (unsigned)__builtin_amdgcn_update_dpp(0, (int)x, 0x112, 0xF, 0xF, true); x = x > t ? x : t; // row_shr:2
    t = (unsigned)__builtin_amdgcn_update_dpp(0, (int)x, 0x114, 0xF, 0xF, true); x = x > t ? x : t; // row_shr:4
    t = (unsigned)__builtin_amdgcn_update_dpp(0, (int)x, 0x118, 0xF, 0xF, true); x = x > t ? x : t; // row_shr:8
    t = (unsigned)__builtin_amdgcn_update_dpp(0, (int)x, 0x142, 0xA, 0xF, true); x = x > t ? x : t; // row_bcast:15
    t = (unsigned)__builtin_amdgcn_update_dpp(0, (int)x, 0x143, 0xC, 0xF, true); x = x > t ? x : t; // row_bcast:31
    return (unsigned)__builtin_amdgcn_readlane((int)x, 63);
}

// broadcast float from lane sl (wave-uniform SGPR) — pure bit ops, no alloca
__device__ __forceinline__ float bcastf(float v, int sl) {
    return __int_as_float(__builtin_amdgcn_readlane(__float_as_int(v), sl));
}

// ---------------------------------------------------------------------------
// Stage 1: one wave per (batch,channel) system. Lane r owns row r of the
// 36x37 augmented matrix in 37 NAMED fp32 scalars rr0..rr36 — no array, so
// nothing can be demoted to scratch. Gauss-Jordan WITH partial pivoting.
// BUG FIX vs R8/R9: the LDS knot staging loaded only 64 of the 96 floats
// (knots 22..31 were garbage) — that, not pivoting, was the absmax blow-up.
// ---------------------------------------------------------------------------
__global__ __launch_bounds__(64, 1) void tps_solve(const float* __restrict__ params,
                                                   float* __restrict__ Wout) {
    int sys = blockIdx.x;
    int b   = sys / 3;
    int ch  = sys % 3;
    const float* pp = params + (size_t)b * (6 * NK + 3);

    __shared__ float sxs[NK * 3];
    int lane = threadIdx.x;
    #pragma unroll
    for (int i = lane; i < NK * 3; i += 64) sxs[i] = pp[i];   // ALL 96 floats
    __syncthreads();

    float lam = pp[6 * NK + ch];

    // my knot coords (lanes 0..31); junk-but-finite elsewhere
    int li = (lane < NK) ? lane : 0;
    float myx0 = sxs[li*3+0], myx1 = sxs[li*3+1], myx2 = sxs[li*3+2];

    // ---- build row: 37 named scalars ----
    float rr0,rr1,rr2,rr3,rr4,rr5,rr6,rr7,rr8,rr9,rr10,rr11,rr12,rr13,rr14,
          rr15,rr16,rr17,rr18,rr19,rr20,rr21,rr22,rr23,rr24,rr25,rr26,rr27,
          rr28,rr29,rr30,rr31,rr32,rr33,rr34,rr35,rr36;

    float bcomp = (lane == 33) ? 0.f : (lane == 34) ? 1.f : 2.f;  // coord idx
#define BUILDC(c) do {                                                        \
    float xc0 = sxs[(c)*3+0], xc1 = sxs[(c)*3+1], xc2 = sxs[(c)*3+2];         \
    float dx = myx0 - xc0, dy = myx1 - xc1, dz = myx2 - xc2;                  \
    float d  = hw_sqrtf(dx*dx + dy*dy + dz*dz);                               \
    float v;                                                                  \
    if (lane < NK)       v = (lane == (c)) ? lam : d;                         \
    else if (lane == 32) v = 1.0f;                                            \
    else if (lane < NP)  v = (bcomp==0.f)?xc0:(bcomp==1.f)?xc1:xc2;           \
    else                 v = 0.0f;                                            \
    rr##c = v;                                                                \
} while (0)
    BUILDC(0);  BUILDC(1);  BUILDC(2);  BUILDC(3);  BUILDC(4);  BUILDC(5);
    BUILDC(6);  BUILDC(7);  BUILDC(8);  BUILDC(9);  BUILDC(10); BUILDC(11);
    BUILDC(12); BUILDC(13); BUILDC(14); BUILDC(15); BUILDC(16); BUILDC(17);
    BUILDC(18); BUILDC(19); BUILDC(20); BUILDC(21); BUILDC(22); BUILDC(23);
    BUILDC(24); BUILDC(25); BUILDC(26); BUILDC(27); BUILDC(28); BUILDC(29);
    BUILDC(30); BUILDC(31);
#undef BUILDC
    bool top = (lane < NK);
    rr32 = top ? 1.0f : 0.0f;
    rr33 = top ? myx0 : 0.0f;
    rr34 = top ? myx1 : 0.0f;
    rr35 = top ? myx2 : 0.0f;
    rr36 = top ? pp[3*NK + li*3 + ch] : 0.0f;   // rhs = ys[lane][ch]

    // ---- Gauss-Jordan with partial pivoting; 36 straight-line steps ----
    unsigned used = (lane >= NP) ? 1u : 0u;   // lanes 36..63 never pivot
    int kown = -1;

#define COLU(c) if ((c) > KK) {                                  \
    float pc = bcastf(rr##c, prid) * inv;                        \
    rr##c = isp ? pc : rr##c - f * pc;                           \
}
#define ALLCOLS \
    COLU(1)  COLU(2)  COLU(3)  COLU(4)  COLU(5)  COLU(6)  COLU(7)  COLU(8)  \
    COLU(9)  COLU(10) COLU(11) COLU(12) COLU(13) COLU(14) COLU(15) COLU(16) \
    COLU(17) COLU(18) COLU(19) COLU(20) COLU(21) COLU(22) COLU(23) COLU(24) \
    COLU(25) COLU(26) COLU(27) COLU(28) COLU(29) COLU(30) COLU(31) COLU(32) \
    COLU(33) COLU(34) COLU(35) COLU(36)
#define STEP(Kv) do {                                                         \
    const int KK = (Kv);                                                      \
    unsigned pk_ = (__float_as_uint(fabsf(rr##Kv)) & 0xFFFFFFC0u)             \
                 | (unsigned)lane;                                            \
    pk_ = used ? 0u : pk_;                                                    \
    int prid  = (int)(wave_max64(pk_) & 63u);                                 \
    float pv  = bcastf(rr##Kv, prid);                                         \
    float inv = 1.0f / pv;                                                    \
    float f   = rr##Kv;                                                       \
    bool  isp = (lane == prid);                                               \
    if (isp) { used = 1u; kown = (Kv); }                                      \
    ALLCOLS                                                                   \
} while (0)

    STEP(0);  STEP(1);  STEP(2);  STEP(3);  STEP(4);  STEP(5);
    STEP(6);  STEP(7);  STEP(8);  STEP(9);  STEP(10); STEP(11);
    STEP(12); STEP(13); STEP(14); STEP(15); STEP(16); STEP(17);
    STEP(18); STEP(19); STEP(20); STEP(21); STEP(22); STEP(23);
    STEP(24); STEP(25); STEP(26); STEP(27); STEP(28); STEP(29);
    STEP(30); STEP(31); STEP(32); STEP(33); STEP(34); STEP(35);
#undef STEP
#undef ALLCOLS
#undef COLU

    // lane chosen at step k holds x[k] = rr36 (its row was normalized)
    if (kown >= 0)
        Wout[((size_t)b * NP + kown) * 4 + ch] = rr36;
}

// ---------------------------------------------------------------------------
// Stage 2: per-pixel spline evaluation, PX=8 pixels (24 floats = 6 float4)
// per thread. fimg = raw.reshape(B,HW,3) is a linear reinterpretation, and
// the output reshape is the identity on flat layout. (unchanged — near its
// HBM roofline at ~7 us)
// ---------------------------------------------------------------------------
__global__ __launch_bounds__(256) void spline_apply(const float* __restrict__ raw,
                                                    const float* __restrict__ params,
                                                    const float4* __restrict__ Wk,
                                                    float* __restrict__ out,
                                                    int HW) {
    __shared__ float4 sX[NK];
    __shared__ float4 sW[NP];

    int b   = blockIdx.y;
    int tid = threadIdx.x;

    const float* pp = params + (size_t)b * (6 * NK + 3);
    if (tid < NK) sX[tid] = make_float4(pp[tid*3], pp[tid*3+1], pp[tid*3+2], 0.f);
    if (tid < NP) sW[tid] = Wk[(size_t)b * NP + tid];
    __syncthreads();

    int p8 = blockIdx.x * 256 + tid;          // 8-pixel group within batch
    if (p8 * PX >= HW) return;

    size_t off = (size_t)b * HW * 3 + (size_t)p8 * (PX * 3);
    const float4* src = (const float4*)(raw + off);
    float f[PX * 3];
    #pragma unroll
    for (int j = 0; j < PX * 3 / 4; ++j) {
        float4 v = src[j];
        f[j*4+0] = v.x; f[j*4+1] = v.y; f[j*4+2] = v.z; f[j*4+3] = v.w;
    }

    float4 wb  = sW[NK];                                    // bias row
    float4 w33 = sW[NK+1], w34 = sW[NK+2], w35 = sW[NK+3];  // linear rows
    float acc[PX * 3];
    #pragma unroll
    for (int p = 0; p < PX; ++p) {
        float c0 = f[p*3+0], c1 = f[p*3+1], c2 = f[p*3+2];
        acc[p*3+0] = wb.x + c0*w33.x + c1*w34.x + c2*w35.x;
        acc[p*3+1] = wb.y + c0*w33.y + c1*w34.y + c2*w35.y;
        acc[p*3+2] = wb.z + c0*w33.z + c1*w34.z + c2*w35.z;
    }

    #pragma unroll 4
    for (int k = 0; k < NK; ++k) {
        float4 x = sX[k];
        float4 w = sW[k];
        #pragma unroll
        for (int p = 0; p < PX; ++p) {
            float dx = f[p*3+0] - x.x;
            float dy = f[p*3+1] - x.y;
            float dz = f[p*3+2] - x.z;
            float d  = hw_sqrtf(dx*dx + dy*dy + dz*dz);
            acc[p*3+0] += d * w.x;
            acc[p*3+1] += d * w.y;
            acc[p*3+2] += d * w.z;
        }
    }

    float4* dst = (float4*)(out + off);
    #pragma unroll
    for (int j = 0; j < PX * 3 / 4; ++j)
        dst[j] = make_float4(acc[j*4+0], acc[j*4+1], acc[j*4+2], acc[j*4+3]);
}

extern "C" void kernel_launch(void* const* d_in, const int* in_sizes, int n_in,
                              void* d_out, int out_size, void* d_ws, size_t ws_size,
                              hipStream_t stream) {
    const float* raw    = (const float*)d_in[0];
    const float* params = (const float*)d_in[1];
    float* out = (float*)d_out;
    float* Wk  = (float*)d_ws;                 // [B][36][4] floats

    int B  = in_sizes[1] / (6 * NK + 3);
    int HW = in_sizes[0] / (B * 3);

    tps_solve<<<dim3(B * 3), dim3(64), 0, stream>>>(params, Wk);

    int groups = HW / PX;                      // HW = 200704, divisible by 8
    int bpb = (groups + 255) / 256;
    spline_apply<<<dim3(bpb, B), dim3(256), 0, stream>>>(
        raw, params, (const float4*)Wk, out, HW);
}